// Round 18
// baseline (306.081 us; speedup 1.0000x reference)
//
#include <hip/hip_runtime.h>
#include <cstdint>

// MultiheadRCDA: N=8, L=300, HH=WW=96, E=256, NH=8, HD=32
// Round 18: attn v4 — block=(bn,h/4), V h-tiles GLL-staged in LDS and shared
// by all 8 waves (V read once chip-wide; exact vmcnt(1) pipeline; XOR-swizzled
// granules both-sides). vpm = vproj + means tail-phase in identical blocks.

typedef __attribute__((ext_vector_type(8))) short short8v;  // bf16x8 MFMA frag
typedef __attribute__((ext_vector_type(4))) short short4v;  // 8B packed bf16
typedef __attribute__((ext_vector_type(4))) float f32x4;

#define SCALE_Q 0.17677669529663687f  // 32^-0.5

#define GLL16(gp, lp)                                                   \
  __builtin_amdgcn_global_load_lds(                                     \
      (const __attribute__((address_space(1))) void*)(gp),              \
      (__attribute__((address_space(3))) void*)(lp), 16, 0, 0)

__device__ __forceinline__ unsigned short f2bf(float x) {
  unsigned int u = __builtin_bit_cast(unsigned int, x);
  u += 0x7FFFu + ((u >> 16) & 1u);
  return (unsigned short)(u >> 16);
}

__device__ __forceinline__ unsigned int cvtpk(float a, float b) {
  unsigned int r;
  asm("v_cvt_pk_bf16_f32 %0, %1, %2" : "=v"(r) : "v"(a), "v"(b));
  return r;
}

__device__ __forceinline__ short8v pack8cvt(const f32x4& lo, const f32x4& hi) {
  union { short8v s; unsigned int u[4]; } z;
  z.u[0] = cvtpk(lo[0], lo[1]);
  z.u[1] = cvtpk(lo[2], lo[3]);
  z.u[2] = cvtpk(hi[0], hi[1]);
  z.u[3] = cvtpk(hi[2], hi[3]);
  return z.s;
}

__device__ __forceinline__ short4v pack4cvt(float a, float b, float c, float d) {
  union { short4v s; unsigned int u[2]; } z;
  z.u[0] = cvtpk(a, b);
  z.u[1] = cvtpk(c, d);
  return z.s;
}

__device__ __forceinline__ short8v pack8(const float4& fa, const float4& fb) {
  short8v v;
  v[0] = (short)f2bf(fa.x); v[1] = (short)f2bf(fa.y);
  v[2] = (short)f2bf(fa.z); v[3] = (short)f2bf(fa.w);
  v[4] = (short)f2bf(fb.x); v[5] = (short)f2bf(fb.y);
  v[6] = (short)f2bf(fb.z); v[7] = (short)f2bf(fb.w);
  return v;
}

// ---------------- weight fp32->bf16 ----------------
__global__ __launch_bounds__(256) void cvt_w_kernel(const float* __restrict__ w_in,
                                                    const float* __restrict__ w_out,
                                                    short* __restrict__ Wb) {
  int idx = blockIdx.x * 256 + threadIdx.x;  // 393216 total
  float v = (idx < 327680) ? w_in[idx] : w_out[idx - 327680];
  Wb[idx] = (short)f2bf(v);
}

// ---------------- vpm: vproj (r16 body) + means tail phase ----------------
// 768 blocks x 512 thr. vproj: 96 rows/block, 6 tiles, 8 waves x 32 channels,
// AGPR-pinned B, counted vmcnt, pair stores. Tail: block id does 2 mean rows.
__global__ __launch_bounds__(512, 4) void vpm_kernel(
    const float* __restrict__ A, const short* __restrict__ Wb,
    const float* __restrict__ bias, short* __restrict__ vvT,
    const float* __restrict__ key_row, const float* __restrict__ key_col,
    float* __restrict__ krm, float* __restrict__ kcm) {
  __shared__ float buf[2][16 * 260];   // 33.3 KB
  __shared__ short Ts[8][32 * 36];     // 18.4 KB
  int t = threadIdx.x;
  int wave = t >> 6, lane = t & 63, r = lane & 15, g = lane >> 4;
  int m0g = blockIdx.x * 96;
  int b_ = blockIdx.x / 96;
  int hw00 = (blockIdx.x - b_ * 96) * 96;
  int chbase = wave * 32;

  short8v bf[8][2];
  {
    const short* wbase = Wb + (size_t)(chbase + r) * 256;
#pragma unroll
    for (int ks = 0; ks < 8; ++ks)
#pragma unroll
      for (int nf = 0; nf < 2; ++nf)
        bf[ks][nf] = *(const short8v*)(wbase + nf * 16 * 256 + ks * 32 + g * 8);
  }
#pragma unroll
  for (int ks = 0; ks < 8; ++ks)
#pragma unroll
    for (int nf = 0; nf < 2; ++nf)
      asm volatile("" : "+a"(bf[ks][nf]));
  float bias_v[2];
#pragma unroll
  for (int nf = 0; nf < 2; ++nf) bias_v[nf] = bias[chbase + nf * 16 + r];

#pragma unroll
  for (int q = 0; q < 2; ++q) {
#pragma unroll
    for (int i = 0; i < 2; ++i) {
      int row = wave * 2 + i;
      const float* gp = A + ((size_t)m0g + q * 16 + row) * 256 + lane * 4;
      GLL16(gp, &buf[q][row * 260]);
    }
  }

  int chg = chbase + (lane & 31);
  int half = lane >> 5;
  short* vbase = vvT + (size_t)(b_ * 8 + (chg >> 5)) * 294912 +
                 (size_t)(chg & 31) * 9216 + hw00;
  const short* tsr = &Ts[wave][(lane & 31) * 36];

#pragma unroll
  for (int tt = 0; tt < 6; ++tt) {
    if (tt == 5)                  asm volatile("s_waitcnt vmcnt(0)" ::: "memory");
    else if (tt == 2 || tt == 4)  asm volatile("s_waitcnt vmcnt(4)" ::: "memory");
    else                          asm volatile("s_waitcnt vmcnt(2)" ::: "memory");
    __builtin_amdgcn_s_barrier();

    f32x4 acc[2] = {};
    const float* bp_ = &buf[tt & 1][0];
#pragma unroll
    for (int ks = 0; ks < 8; ++ks) {
      const float* p = bp_ + r * 260 + ks * 32 + g * 8;
      f32x4 lo = *(const f32x4*)p;
      f32x4 hi = *(const f32x4*)(p + 4);
      short8v af = pack8cvt(lo, hi);
      acc[0] = __builtin_amdgcn_mfma_f32_16x16x32_bf16(af, bf[ks][0], acc[0], 0, 0, 0);
      acc[1] = __builtin_amdgcn_mfma_f32_16x16x32_bf16(af, bf[ks][1], acc[1], 0, 0, 0);
    }

#pragma unroll
    for (int nf = 0; nf < 2; ++nf) {
      float bv = bias_v[nf];
      *(short4v*)&Ts[wave][(nf * 16 + r) * 36 + (tt & 1) * 16 + g * 4] =
          pack4cvt(acc[nf][0] + bv, acc[nf][1] + bv, acc[nf][2] + bv, acc[nf][3] + bv);
    }
    asm volatile("" ::: "memory");

    if (tt & 1) {
      short* gdst = vbase + (tt - 1) * 16 + half * 16;
      const short* src = tsr + half * 16;
      *(short8v*)gdst = *(const short8v*)src;
      *(short8v*)(gdst + 8) = *(const short8v*)(src + 8);
      asm volatile("" ::: "memory");
    }

    __builtin_amdgcn_s_barrier();
    if (tt + 2 < 6) {
#pragma unroll
      for (int i = 0; i < 2; ++i) {
        int row = wave * 2 + i;
        const float* gp = A + ((size_t)m0g + (tt + 2) * 16 + row) * 256 + lane * 4;
        GLL16(gp, &buf[tt & 1][row * 260]);
      }
    }
  }

  // ---------------- means tail phase: 2 rows per block ----------------
  __syncthreads();
  int id = blockIdx.x;
  int sub = t >> 8, u = t & 255;
  int e4 = u & 63, q4 = u >> 6;
  float4* part4 = (float4*)&buf[0][0];
  if (id < 384) {
    int bw = id * 2 + sub;  // b*96+w
    int b = bw / 96, w = bw - b * 96;
    const float4* p = (const float4*)(key_row + ((size_t)b * 9216 + w) * 256) +
                      e4 + (size_t)q4 * 24 * 6144;
    float4 s = {0.f, 0.f, 0.f, 0.f};
#pragma unroll
    for (int i = 0; i < 24; ++i) {
      float4 v = p[(size_t)i * 6144];
      s.x += v.x; s.y += v.y; s.z += v.z; s.w += v.w;
    }
    part4[sub * 256 + u] = s;
    __syncthreads();
    if (u < 64) {
      float4 a = part4[sub * 256 + u], c = part4[sub * 256 + u + 64];
      float4 d = part4[sub * 256 + u + 128], e = part4[sub * 256 + u + 192];
      float4 o;
      o.x = (a.x + c.x + d.x + e.x) * (1.f / 96.f);
      o.y = (a.y + c.y + d.y + e.y) * (1.f / 96.f);
      o.z = (a.z + c.z + d.z + e.z) * (1.f / 96.f);
      o.w = (a.w + c.w + d.w + e.w) * (1.f / 96.f);
      ((float4*)krm)[(size_t)bw * 64 + u] = o;
    }
  } else {
    int bh = (id - 384) * 2 + sub;  // b*96+h
    const float4* p = (const float4*)(key_col + (size_t)bh * 24576) + e4 +
                      (size_t)q4 * 24 * 64;
    float4 s = {0.f, 0.f, 0.f, 0.f};
#pragma unroll
    for (int i = 0; i < 24; ++i) {
      float4 v = p[(size_t)i * 64];
      s.x += v.x; s.y += v.y; s.z += v.z; s.w += v.w;
    }
    part4[sub * 256 + u] = s;
    __syncthreads();
    if (u < 64) {
      float4 a = part4[sub * 256 + u], c = part4[sub * 256 + u + 64];
      float4 d = part4[sub * 256 + u + 128], e = part4[sub * 256 + u + 192];
      float4 o;
      o.x = (a.x + c.x + d.x + e.x) * (1.f / 96.f);
      o.y = (a.y + c.y + d.y + e.y) * (1.f / 96.f);
      o.z = (a.z + c.z + d.z + e.z) * (1.f / 96.f);
      o.w = (a.w + c.w + d.w + e.w) * (1.f / 96.f);
      ((float4*)kcm)[(size_t)bh * 64 + u] = o;
    }
  }
}

// ---------------- gemm512: kproj + qproj in one launch ----------------
__global__ __launch_bounds__(512) void gemm512(
    const float* __restrict__ krm, const float* __restrict__ kcm,
    const float* __restrict__ qrow, const float* __restrict__ qcol,
    const short* __restrict__ Wb, const float* __restrict__ Bv,
    short* __restrict__ krb, short* __restrict__ kcb,
    short* __restrict__ qrb, short* __restrict__ qcb) {
  __shared__ short As[2][32 * 264];
  int id = blockIdx.x;
  const float* A; short* Cb; const short* Wp; const float* bp; int M, m064;
  float scale;
  if (id < 12)      { A = krm;  Cb = krb; Wp = Wb + 131072; bp = Bv + 512; M = 768;  m064 = id * 64;        scale = 1.f; }
  else if (id < 24) { A = kcm;  Cb = kcb; Wp = Wb + 196608; bp = Bv + 768; M = 768;  m064 = (id - 12) * 64; scale = 1.f; }
  else if (id < 62) { A = qrow; Cb = qrb; Wp = Wb;          bp = Bv;       M = 2400; m064 = (id - 24) * 64; scale = SCALE_Q; }
  else              { A = qcol; Cb = qcb; Wp = Wb + 65536;  bp = Bv + 256; M = 2400; m064 = (id - 62) * 64; scale = SCALE_Q; }

  int t = threadIdx.x, sub = t >> 8, u = t & 255;
  int wave = u >> 6, lane = u & 63, r = lane & 15, g = lane >> 4;
  int m0 = m064 + sub * 32;

  {
    int row = u >> 3, c0 = (u & 7) * 32;
    int mrow = m0 + row; if (mrow >= M) mrow = M - 1;
    const float* ap = A + (size_t)mrow * 256 + c0;
    float4 ld[8];
#pragma unroll
    for (int j = 0; j < 8; ++j) ld[j] = *(const float4*)(ap + j * 4);
    short* dst = &As[sub][row * 264 + c0];
#pragma unroll
    for (int j = 0; j < 4; ++j)
      *(short8v*)(dst + j * 8) = pack8(ld[2 * j], ld[2 * j + 1]);
  }
  __syncthreads();

  f32x4 acc[2][4] = {};
  const short* wbase = Wp + (size_t)(wave * 64 + r) * 256;
#pragma unroll
  for (int ks = 0; ks < 8; ++ks) {
    short8v af0 = *(const short8v*)&As[sub][r * 264 + ks * 32 + g * 8];
    short8v af1 = *(const short8v*)&As[sub][(16 + r) * 264 + ks * 32 + g * 8];
    short8v bfr[4];
#pragma unroll
    for (int nf = 0; nf < 4; ++nf)
      bfr[nf] = *(const short8v*)(wbase + nf * 16 * 256 + ks * 32 + g * 8);
#pragma unroll
    for (int nf = 0; nf < 4; ++nf) {
      acc[0][nf] = __builtin_amdgcn_mfma_f32_16x16x32_bf16(af0, bfr[nf], acc[0][nf], 0, 0, 0);
      acc[1][nf] = __builtin_amdgcn_mfma_f32_16x16x32_bf16(af1, bfr[nf], acc[1][nf], 0, 0, 0);
    }
  }

#pragma unroll
  for (int mf = 0; mf < 2; ++mf)
#pragma unroll
    for (int nf = 0; nf < 4; ++nf) {
      int nn = wave * 64 + nf * 16 + r;
      float bval = bp[nn];
#pragma unroll
      for (int i = 0; i < 4; ++i) {
        int m = m0 + mf * 16 + g * 4 + i;
        if (m >= M) continue;
        Cb[(size_t)m * 256 + nn] = (short)f2bf((acc[mf][nf][i] + bval) * scale);
      }
    }
}

// ---------------- out-projection: (p0+p1+p2+p3) @ Wout^T + Bout ----------------
__global__ __launch_bounds__(512) void gemm512_out(
    const float* __restrict__ p0, const float* __restrict__ p1,
    const float* __restrict__ p2, const float* __restrict__ p3,
    const short* __restrict__ Wp, const float* __restrict__ bp,
    float* __restrict__ Cf) {
  __shared__ short As[2][32 * 264];
  const int M = 2400;
  int t = threadIdx.x, sub = t >> 8, u = t & 255;
  int wave = u >> 6, lane = u & 63, r = lane & 15, g = lane >> 4;
  int m0 = blockIdx.x * 64 + sub * 32;

  {
    int row = u >> 3, c0 = (u & 7) * 32;
    int mrow = m0 + row; if (mrow >= M) mrow = M - 1;
    size_t off = (size_t)mrow * 256 + c0;
    float4 ld[8];
#pragma unroll
    for (int j = 0; j < 8; ++j) {
      float4 x = *(const float4*)(p0 + off + j * 4);
      float4 y = *(const float4*)(p1 + off + j * 4);
      float4 z = *(const float4*)(p2 + off + j * 4);
      float4 w = *(const float4*)(p3 + off + j * 4);
      x.x += y.x + z.x + w.x; x.y += y.y + z.y + w.y;
      x.z += y.z + z.z + w.z; x.w += y.w + z.w + w.w;
      ld[j] = x;
    }
    short* dst = &As[sub][row * 264 + c0];
#pragma unroll
    for (int j = 0; j < 4; ++j)
      *(short8v*)(dst + j * 8) = pack8(ld[2 * j], ld[2 * j + 1]);
  }
  __syncthreads();

  f32x4 acc[2][4] = {};
  const short* wbase = Wp + (size_t)(wave * 64 + r) * 256;
#pragma unroll
  for (int ks = 0; ks < 8; ++ks) {
    short8v af0 = *(const short8v*)&As[sub][r * 264 + ks * 32 + g * 8];
    short8v af1 = *(const short8v*)&As[sub][(16 + r) * 264 + ks * 32 + g * 8];
    short8v bfr[4];
#pragma unroll
    for (int nf = 0; nf < 4; ++nf)
      bfr[nf] = *(const short8v*)(wbase + nf * 16 * 256 + ks * 32 + g * 8);
#pragma unroll
    for (int nf = 0; nf < 4; ++nf) {
      acc[0][nf] = __builtin_amdgcn_mfma_f32_16x16x32_bf16(af0, bfr[nf], acc[0][nf], 0, 0, 0);
      acc[1][nf] = __builtin_amdgcn_mfma_f32_16x16x32_bf16(af1, bfr[nf], acc[1][nf], 0, 0, 0);
    }
  }

#pragma unroll
  for (int mf = 0; mf < 2; ++mf)
#pragma unroll
    for (int nf = 0; nf < 4; ++nf) {
      int nn = wave * 64 + nf * 16 + r;
      float bval = bp[nn];
#pragma unroll
      for (int i = 0; i < 4; ++i) {
        int m = m0 + mf * 16 + g * 4 + i;
        if (m >= M) continue;
        int bb = m / 300, ll = m - bb * 300;
        Cf[((size_t)ll * 8 + bb) * 256 + nn] = acc[mf][nf][i] + bval;
      }
    }
}

// ---------------- scores + softmax: MFMA + in-register softmax ----------------
__global__ __launch_bounds__(64) void scores_softmax_v2(
    const short* __restrict__ qrb, const short* __restrict__ qcb,
    const short* __restrict__ krb, const short* __restrict__ kcb,
    short* __restrict__ wrowB, float* __restrict__ wcolT) {
  int lchunk = blockIdx.x, bn = blockIdx.y, kind = blockIdx.z;
  int b = bn >> 3, n = bn & 7;
  int lane = threadIdx.x;
  int r = lane & 15, g = lane >> 4;
  const short* qb = kind ? qcb : qrb;
  const short* kb = kind ? kcb : krb;
  int l0 = lchunk * 80;

  short8v a[5], bfr[6];
#pragma unroll
  for (int lf = 0; lf < 5; ++lf) {
    int l = l0 + lf * 16 + r;
    if (l > 299) l = 299;
    a[lf] = *(const short8v*)(qb + ((size_t)b * 300 + l) * 256 + n * 32 + g * 8);
  }
#pragma unroll
  for (int f = 0; f < 6; ++f)
    bfr[f] = *(const short8v*)(kb + ((size_t)b * 96 + f * 16 + r) * 256 + n * 32 + g * 8);

  f32x4 c[5][6];
#pragma unroll
  for (int lf = 0; lf < 5; ++lf)
#pragma unroll
    for (int f = 0; f < 6; ++f) {
      f32x4 z = {};
      c[lf][f] = __builtin_amdgcn_mfma_f32_16x16x32_bf16(a[lf], bfr[f], z, 0, 0, 0);
    }

#pragma unroll
  for (int lf = 0; lf < 5; ++lf)
#pragma unroll
    for (int i = 0; i < 4; ++i) {
      float m = c[lf][0][i];
#pragma unroll
      for (int f = 1; f < 6; ++f) m = fmaxf(m, c[lf][f][i]);
#pragma unroll
      for (int mask = 1; mask <= 8; mask <<= 1) m = fmaxf(m, __shfl_xor(m, mask, 64));
      float e[6], s = 0.f;
#pragma unroll
      for (int f = 0; f < 6; ++f) { e[f] = __expf(c[lf][f][i] - m); s += e[f]; }
#pragma unroll
      for (int mask = 1; mask <= 8; mask <<= 1) s += __shfl_xor(s, mask, 64);
      float inv = 1.f / s;
#pragma unroll
      for (int f = 0; f < 6; ++f) c[lf][f][i] = e[f] * inv;
    }

  if (kind == 0) {
#pragma unroll
    for (int lf = 0; lf < 5; ++lf)
#pragma unroll
      for (int i = 0; i < 4; ++i) {
        int l = l0 + lf * 16 + g * 4 + i;
        bool ok = (l < 300);
#pragma unroll
        for (int f = 0; f < 6; ++f) {
          float wv = ok ? c[lf][f][i] : 0.f;
          wrowB[((size_t)bn * 320 + l) * 96 + f * 16 + r] = (short)f2bf(wv);
        }
      }
  } else {
#pragma unroll
    for (int lf = 0; lf < 5; ++lf)
#pragma unroll
      for (int f = 0; f < 6; ++f) {
        int l = l0 + lf * 16 + g * 4;
        f32x4 wv = c[lf][f];
#pragma unroll
        for (int i = 0; i < 4; ++i) if (l + i >= 300) wv[i] = 0.f;
        *(f32x4*)(wcolT + ((size_t)bn * 96 + f * 16 + r) * 320 + l) = wv;
      }
  }
}

// ---------------- attention v4: block=(bn, h/4); V tiles LDS-shared ----------
// 256 blocks x 512 thr; 8 waves = 2 df x 4 lq(80 l). V h-tile (6KB) GLL-staged
// dbuf, XOR-swizzled granules (both sides); wc (30KB) staged in prologue.
// part[hq][2400][256] fp32, summed in out-proj.
__global__ __launch_bounds__(512, 2) void attn_v4(
    const short* __restrict__ wrowB, const float* __restrict__ wcolT,
    const short* __restrict__ vvT, float* __restrict__ part) {
  __shared__ short Vs[2][384 * 8];   // 2 x 6 KB (granule-linear)
  __shared__ float wcs[24 * 320];    // 30 KB
  int bid = blockIdx.x;
  int xcd = bid & 7, idx = bid >> 3;    // idx 0..31
  int hq = idx & 3, bn = (idx >> 2) * 8 + xcd;  // 4 hq-blocks of bn -> same XCD
  int hbase = hq * 24;
  int b = bn >> 3, n = bn & 7;
  int t = threadIdx.x, wave = t >> 6, lane = t & 63;
  int df = wave & 1, lq = wave >> 1;
  int l0 = lq * 80;
  int r = lane & 15, g = lane >> 4;

  const short* vbn = vvT + (size_t)bn * 294912;

  // prologue staging
  if (wave < 6) {  // V tiles 0,1: wave w covers granules w*64..w*64+63
    int gg = wave * 64 + lane;          // 0..383
    int d = gg / 12, q = gg - d * 12;
    int qs = q ^ (d & 3);
    const short* s0 = vbn + (size_t)d * 9216 + (hbase + 0) * 96 + qs * 8;
    GLL16(s0, &Vs[0][gg * 8]);
    const short* s1 = vbn + (size_t)d * 9216 + (hbase + 1) * 96 + qs * 8;
    GLL16(s1, &Vs[1][gg * 8]);
  } else {         // wc: 24 rows x 320 f32 = 1920 granules; 2 waves x 15 each
    const float* wcsrc = wcolT + ((size_t)bn * 96 + hbase) * 320;
    int c0 = (wave - 6) * 64 + lane;    // 0..127
#pragma unroll
    for (int k = 0; k < 15; ++k) {
      int c = c0 + k * 128;             // 0..1919
      GLL16(wcsrc + c * 4, &wcs[c * 4]);
    }
  }

  // wr A-frags for this wave's 80 l (rows >=300 are zeroed by scores)
  short8v a[5][3];
  const short* wr = wrowB + (size_t)bn * 320 * 96;
#pragma unroll
  for (int lf = 0; lf < 5; ++lf)
#pragma unroll
    for (int ks = 0; ks < 3; ++ks)
      a[lf][ks] = *(const short8v*)(wr + (l0 + lf * 16 + r) * 96 + ks * 32 + g * 8);

  f32x4 acc[5] = {};
  int d = df * 16 + r;
  int sw = d & 3;

#pragma unroll
  for (int hs = 0; hs < 24; ++hs) {
    if (hs < 23) asm volatile("s_waitcnt vmcnt(1)" ::: "memory");
    else         asm volatile("s_waitcnt vmcnt(0)" ::: "memory");
    __builtin_amdgcn_s_barrier();

    const short* vsb = &Vs[hs & 1][0];
    short8v bfr[3];
#pragma unroll
    for (int ks = 0; ks < 3; ++ks) {
      int q = ks * 4 + g;
      bfr[ks] = *(const short8v*)(vsb + ((size_t)d * 12 + (q ^ sw)) * 8);
    }
    f32x4 R[5] = {};
#pragma unroll
    for (int ks = 0; ks < 3; ++ks)
#pragma unroll
      for (int lf = 0; lf < 5; ++lf)
        R[lf] = __builtin_amdgcn_mfma_f32_16x16x32_bf16(a[lf][ks], bfr[ks], R[lf], 0, 0, 0);
#pragma unroll
    for (int lf = 0; lf < 5; ++lf) {
      f32x4 w = *(const f32x4*)&wcs[hs * 320 + l0 + lf * 16 + g * 4];
      acc[lf] += w * R[lf];
    }

    __builtin_amdgcn_s_barrier();
    if (hs + 2 < 24 && wave < 6) {
      int gg = wave * 64 + lane;
      int d2 = gg / 12, q2 = gg - d2 * 12;
      int qs2 = q2 ^ (d2 & 3);
      const short* src = vbn + (size_t)d2 * 9216 + (hbase + hs + 2) * 96 + qs2 * 8;
      GLL16(src, &Vs[hs & 1][gg * 8]);
    }
  }

  // store fp32 partial to part[hq]
  float* po = part + (size_t)hq * 614400 + (size_t)b * 300 * 256 + n * 32 + d;
#pragma unroll
  for (int lf = 0; lf < 5; ++lf)
#pragma unroll
    for (int i2 = 0; i2 < 4; ++i2) {
      int l = l0 + lf * 16 + g * 4 + i2;
      if (l < 300) po[(size_t)l * 256] = acc[lf][i2];
      po += 0;
    }
}

// ---------------- launch ----------------
extern "C" void kernel_launch(void* const* d_in, const int* in_sizes, int n_in,
                              void* d_out, int out_size, void* d_ws, size_t ws_size,
                              hipStream_t stream) {
  const float* query_row = (const float*)d_in[0];
  const float* query_col = (const float*)d_in[1];
  const float* key_row   = (const float*)d_in[2];
  const float* key_col   = (const float*)d_in[3];
  const float* value     = (const float*)d_in[4];
  const float* W         = (const float*)d_in[5];  // (1280,256)
  const float* Bv        = (const float*)d_in[6];  // (1280,)
  const float* Wout      = (const float*)d_in[7];  // (256,256)
  const float* Bout      = (const float*)d_in[8];  // (256,)

  float* ws = (float*)d_ws;
  float* krm   = ws;                        // 196608 f
  float* kcm   = krm + 196608;              // 196608 f
  float* part  = kcm + 196608;              // 4*614400 = 2457600 f
  float* wcolT = part + 2457600;            // 1966080 f
  short* qrb   = (short*)(wcolT + 1966080); // 614400 s
  short* qcb   = qrb + 614400;              // 614400 s
  short* krb   = qcb + 614400;              // 196608 s
  short* kcb   = krb + 196608;              // 196608 s
  short* wrowB = kcb + 196608;              // 1966080 s
  short* vvT   = wrowB + 1966080;           // 18874368 s
  short* Wb    = vvT + 18874368;            // 393216 s

  cvt_w_kernel<<<1536, 256, 0, stream>>>(W, Wout, Wb);
  vpm_kernel<<<768, 512, 0, stream>>>(value, Wb + 262144, Bv + 1024, vvT,
                                      key_row, key_col, krm, kcm);
  gemm512<<<100, 512, 0, stream>>>(krm, kcm, query_row, query_col, Wb, Bv,
                                   krb, kcb, qrb, qcb);
  scores_softmax_v2<<<dim3(4, 64, 2), 64, 0, stream>>>(qrb, qcb, krb, kcb, wrowB, wcolT);
  attn_v4<<<256, 512, 0, stream>>>(wrowB, wcolT, vvT, part);
  gemm512_out<<<38, 512, 0, stream>>>(part, part + 614400, part + 1228800,
                                      part + 1843200, Wb + 327680, Bout,
                                      (float*)d_out);
}

// Round 19
// 158.051 us; speedup vs baseline: 1.9366x; 1.9366x over previous
//
#include <hip/hip_runtime.h>
#include <cstdint>

// MultiheadRCDA: N=8, L=300, HH=WW=96, E=256, NH=8, HD=32
// Round 19: consolidation — best measured pieces only. r16 vproj (44.6us),
// separate means_v3 (13us each), r16 attn h-split (<=44us), r17 merged
// gemm512 projections + 2-part out-proj. No fusion experiments (mega1/attn_v4
// both regressed: heterogeneous blocks break occupancy + vmcnt accounting).

typedef __attribute__((ext_vector_type(8))) short short8v;  // bf16x8 MFMA frag
typedef __attribute__((ext_vector_type(4))) short short4v;  // 8B packed bf16
typedef __attribute__((ext_vector_type(4))) float f32x4;

#define SCALE_Q 0.17677669529663687f  // 32^-0.5

#define GLL16(gp, lp)                                                   \
  __builtin_amdgcn_global_load_lds(                                     \
      (const __attribute__((address_space(1))) void*)(gp),              \
      (__attribute__((address_space(3))) void*)(lp), 16, 0, 0)

__device__ __forceinline__ unsigned short f2bf(float x) {
  unsigned int u = __builtin_bit_cast(unsigned int, x);
  u += 0x7FFFu + ((u >> 16) & 1u);
  return (unsigned short)(u >> 16);
}

__device__ __forceinline__ unsigned int cvtpk(float a, float b) {
  unsigned int r;
  asm("v_cvt_pk_bf16_f32 %0, %1, %2" : "=v"(r) : "v"(a), "v"(b));
  return r;
}

__device__ __forceinline__ short8v pack8cvt(const f32x4& lo, const f32x4& hi) {
  union { short8v s; unsigned int u[4]; } z;
  z.u[0] = cvtpk(lo[0], lo[1]);
  z.u[1] = cvtpk(lo[2], lo[3]);
  z.u[2] = cvtpk(hi[0], hi[1]);
  z.u[3] = cvtpk(hi[2], hi[3]);
  return z.s;
}

__device__ __forceinline__ short4v pack4cvt(float a, float b, float c, float d) {
  union { short4v s; unsigned int u[2]; } z;
  z.u[0] = cvtpk(a, b);
  z.u[1] = cvtpk(c, d);
  return z.s;
}

__device__ __forceinline__ short8v pack8(const float4& fa, const float4& fb) {
  short8v v;
  v[0] = (short)f2bf(fa.x); v[1] = (short)f2bf(fa.y);
  v[2] = (short)f2bf(fa.z); v[3] = (short)f2bf(fa.w);
  v[4] = (short)f2bf(fb.x); v[5] = (short)f2bf(fb.y);
  v[6] = (short)f2bf(fb.z); v[7] = (short)f2bf(fb.w);
  return v;
}

// ---------------- weight fp32->bf16 ----------------
__global__ __launch_bounds__(256) void cvt_w_kernel(const float* __restrict__ w_in,
                                                    const float* __restrict__ w_out,
                                                    short* __restrict__ Wb) {
  int idx = blockIdx.x * 256 + threadIdx.x;  // 393216 total
  float v = (idx < 327680) ? w_in[idx] : w_out[idx - 327680];
  Wb[idx] = (short)f2bf(v);
}

// ---------------- mean kernels v3 ----------------
__global__ __launch_bounds__(256) void mean_over_h_v3(const float* __restrict__ in,
                                                      float* __restrict__ out) {
  __shared__ float4 part[256];
  int bw = blockIdx.x;  // b*96 + w
  int b = bw / 96, w = bw - b * 96;
  int t = threadIdx.x, e4 = t & 63, hq = t >> 6;
  const float4* p = (const float4*)(in + ((size_t)b * 9216 + w) * 256) + e4 +
                    (size_t)hq * 24 * 6144;
  float4 s = {0.f, 0.f, 0.f, 0.f};
#pragma unroll
  for (int i = 0; i < 24; ++i) {
    float4 v = p[(size_t)i * 6144];
    s.x += v.x; s.y += v.y; s.z += v.z; s.w += v.w;
  }
  part[t] = s;
  __syncthreads();
  if (t < 64) {
    float4 a = part[t], c = part[t + 64], d = part[t + 128], e = part[t + 192];
    float4 o;
    o.x = (a.x + c.x + d.x + e.x) * (1.f / 96.f);
    o.y = (a.y + c.y + d.y + e.y) * (1.f / 96.f);
    o.z = (a.z + c.z + d.z + e.z) * (1.f / 96.f);
    o.w = (a.w + c.w + d.w + e.w) * (1.f / 96.f);
    ((float4*)out)[(size_t)bw * 64 + t] = o;
  }
}

__global__ __launch_bounds__(256) void mean_over_w_v3(const float* __restrict__ in,
                                                      float* __restrict__ out) {
  __shared__ float4 part[256];
  int bh = blockIdx.x;  // b*96 + h
  int t = threadIdx.x, e4 = t & 63, wq = t >> 6;
  const float4* p = (const float4*)(in + (size_t)bh * 24576) + e4 + (size_t)wq * 24 * 64;
  float4 s = {0.f, 0.f, 0.f, 0.f};
#pragma unroll
  for (int i = 0; i < 24; ++i) {
    float4 v = p[(size_t)i * 64];
    s.x += v.x; s.y += v.y; s.z += v.z; s.w += v.w;
  }
  part[t] = s;
  __syncthreads();
  if (t < 64) {
    float4 a = part[t], c = part[t + 64], d = part[t + 128], e = part[t + 192];
    float4 o;
    o.x = (a.x + c.x + d.x + e.x) * (1.f / 96.f);
    o.y = (a.y + c.y + d.y + e.y) * (1.f / 96.f);
    o.z = (a.z + c.z + d.z + e.z) * (1.f / 96.f);
    o.w = (a.w + c.w + d.w + e.w) * (1.f / 96.f);
    ((float4*)out)[(size_t)bh * 64 + t] = o;
  }
}

// ---------------- value projection (r16: 3 blocks/CU) ----------------
// vvT[bn][d(32)][hw(9216)] bf16. grid 768 x 512 thr; 96 rows/block
// (6 tiles of 16); 8 waves x 32 channels; AGPR-pinned B; counted vmcnt.
__global__ __launch_bounds__(512, 4) void vproj_kernel(
    const float* __restrict__ A, const short* __restrict__ Wb,
    const float* __restrict__ bias, short* __restrict__ vvT) {
  __shared__ float buf[2][16 * 260];   // 33.3 KB
  __shared__ short Ts[8][32 * 36];     // 18.4 KB
  int t = threadIdx.x;
  int wave = t >> 6, lane = t & 63, r = lane & 15, g = lane >> 4;
  int m0g = blockIdx.x * 96;
  int b_ = blockIdx.x / 96;
  int hw00 = (blockIdx.x - b_ * 96) * 96;
  int chbase = wave * 32;

  short8v bf[8][2];
  {
    const short* wbase = Wb + (size_t)(chbase + r) * 256;
#pragma unroll
    for (int ks = 0; ks < 8; ++ks)
#pragma unroll
      for (int nf = 0; nf < 2; ++nf)
        bf[ks][nf] = *(const short8v*)(wbase + nf * 16 * 256 + ks * 32 + g * 8);
  }
#pragma unroll
  for (int ks = 0; ks < 8; ++ks)
#pragma unroll
    for (int nf = 0; nf < 2; ++nf)
      asm volatile("" : "+a"(bf[ks][nf]));
  float bias_v[2];
#pragma unroll
  for (int nf = 0; nf < 2; ++nf) bias_v[nf] = bias[chbase + nf * 16 + r];

#pragma unroll
  for (int q = 0; q < 2; ++q) {
#pragma unroll
    for (int i = 0; i < 2; ++i) {
      int row = wave * 2 + i;
      const float* gp = A + ((size_t)m0g + q * 16 + row) * 256 + lane * 4;
      GLL16(gp, &buf[q][row * 260]);
    }
  }

  int chg = chbase + (lane & 31);
  int half = lane >> 5;
  short* vbase = vvT + (size_t)(b_ * 8 + (chg >> 5)) * 294912 +
                 (size_t)(chg & 31) * 9216 + hw00;
  const short* tsr = &Ts[wave][(lane & 31) * 36];

#pragma unroll
  for (int tt = 0; tt < 6; ++tt) {
    if (tt == 5)                  asm volatile("s_waitcnt vmcnt(0)" ::: "memory");
    else if (tt == 2 || tt == 4)  asm volatile("s_waitcnt vmcnt(4)" ::: "memory");
    else                          asm volatile("s_waitcnt vmcnt(2)" ::: "memory");
    __builtin_amdgcn_s_barrier();

    f32x4 acc[2] = {};
    const float* bp_ = &buf[tt & 1][0];
#pragma unroll
    for (int ks = 0; ks < 8; ++ks) {
      const float* p = bp_ + r * 260 + ks * 32 + g * 8;
      f32x4 lo = *(const f32x4*)p;
      f32x4 hi = *(const f32x4*)(p + 4);
      short8v af = pack8cvt(lo, hi);
      acc[0] = __builtin_amdgcn_mfma_f32_16x16x32_bf16(af, bf[ks][0], acc[0], 0, 0, 0);
      acc[1] = __builtin_amdgcn_mfma_f32_16x16x32_bf16(af, bf[ks][1], acc[1], 0, 0, 0);
    }

#pragma unroll
    for (int nf = 0; nf < 2; ++nf) {
      float bv = bias_v[nf];
      *(short4v*)&Ts[wave][(nf * 16 + r) * 36 + (tt & 1) * 16 + g * 4] =
          pack4cvt(acc[nf][0] + bv, acc[nf][1] + bv, acc[nf][2] + bv, acc[nf][3] + bv);
    }
    asm volatile("" ::: "memory");

    if (tt & 1) {  // store tiles (tt-1, tt): 32 hw = 64B per channel
      short* gdst = vbase + (tt - 1) * 16 + half * 16;
      const short* src = tsr + half * 16;
      *(short8v*)gdst = *(const short8v*)src;
      *(short8v*)(gdst + 8) = *(const short8v*)(src + 8);
      asm volatile("" ::: "memory");
    }

    __builtin_amdgcn_s_barrier();
    if (tt + 2 < 6) {
#pragma unroll
      for (int i = 0; i < 2; ++i) {
        int row = wave * 2 + i;
        const float* gp = A + ((size_t)m0g + (tt + 2) * 16 + row) * 256 + lane * 4;
        GLL16(gp, &buf[tt & 1][row * 260]);
      }
    }
  }
}

// ---------------- gemm512: kproj + qproj in one launch ----------------
__global__ __launch_bounds__(512) void gemm512(
    const float* __restrict__ krm, const float* __restrict__ kcm,
    const float* __restrict__ qrow, const float* __restrict__ qcol,
    const short* __restrict__ Wb, const float* __restrict__ Bv,
    short* __restrict__ krb, short* __restrict__ kcb,
    short* __restrict__ qrb, short* __restrict__ qcb) {
  __shared__ short As[2][32 * 264];
  int id = blockIdx.x;
  const float* A; short* Cb; const short* Wp; const float* bp; int M, m064;
  float scale;
  if (id < 12)      { A = krm;  Cb = krb; Wp = Wb + 131072; bp = Bv + 512; M = 768;  m064 = id * 64;        scale = 1.f; }
  else if (id < 24) { A = kcm;  Cb = kcb; Wp = Wb + 196608; bp = Bv + 768; M = 768;  m064 = (id - 12) * 64; scale = 1.f; }
  else if (id < 62) { A = qrow; Cb = qrb; Wp = Wb;          bp = Bv;       M = 2400; m064 = (id - 24) * 64; scale = SCALE_Q; }
  else              { A = qcol; Cb = qcb; Wp = Wb + 65536;  bp = Bv + 256; M = 2400; m064 = (id - 62) * 64; scale = SCALE_Q; }

  int t = threadIdx.x, sub = t >> 8, u = t & 255;
  int wave = u >> 6, lane = u & 63, r = lane & 15, g = lane >> 4;
  int m0 = m064 + sub * 32;

  {
    int row = u >> 3, c0 = (u & 7) * 32;
    int mrow = m0 + row; if (mrow >= M) mrow = M - 1;
    const float* ap = A + (size_t)mrow * 256 + c0;
    float4 ld[8];
#pragma unroll
    for (int j = 0; j < 8; ++j) ld[j] = *(const float4*)(ap + j * 4);
    short* dst = &As[sub][row * 264 + c0];
#pragma unroll
    for (int j = 0; j < 4; ++j)
      *(short8v*)(dst + j * 8) = pack8(ld[2 * j], ld[2 * j + 1]);
  }
  __syncthreads();

  f32x4 acc[2][4] = {};
  const short* wbase = Wp + (size_t)(wave * 64 + r) * 256;
#pragma unroll
  for (int ks = 0; ks < 8; ++ks) {
    short8v af0 = *(const short8v*)&As[sub][r * 264 + ks * 32 + g * 8];
    short8v af1 = *(const short8v*)&As[sub][(16 + r) * 264 + ks * 32 + g * 8];
    short8v bfr[4];
#pragma unroll
    for (int nf = 0; nf < 4; ++nf)
      bfr[nf] = *(const short8v*)(wbase + nf * 16 * 256 + ks * 32 + g * 8);
#pragma unroll
    for (int nf = 0; nf < 4; ++nf) {
      acc[0][nf] = __builtin_amdgcn_mfma_f32_16x16x32_bf16(af0, bfr[nf], acc[0][nf], 0, 0, 0);
      acc[1][nf] = __builtin_amdgcn_mfma_f32_16x16x32_bf16(af1, bfr[nf], acc[1][nf], 0, 0, 0);
    }
  }

#pragma unroll
  for (int mf = 0; mf < 2; ++mf)
#pragma unroll
    for (int nf = 0; nf < 4; ++nf) {
      int nn = wave * 64 + nf * 16 + r;
      float bval = bp[nn];
#pragma unroll
      for (int i = 0; i < 4; ++i) {
        int m = m0 + mf * 16 + g * 4 + i;
        if (m >= M) continue;
        Cb[(size_t)m * 256 + nn] = (short)f2bf((acc[mf][nf][i] + bval) * scale);
      }
    }
}

// ---------------- out-projection: (part0+part1) @ Wout^T + Bout ----------------
__global__ __launch_bounds__(512) void gemm512_out(
    const float* __restrict__ p0, const float* __restrict__ p1,
    const short* __restrict__ Wp, const float* __restrict__ bp,
    float* __restrict__ Cf) {
  __shared__ short As[2][32 * 264];
  const int M = 2400;
  int t = threadIdx.x, sub = t >> 8, u = t & 255;
  int wave = u >> 6, lane = u & 63, r = lane & 15, g = lane >> 4;
  int m0 = blockIdx.x * 64 + sub * 32;

  {
    int row = u >> 3, c0 = (u & 7) * 32;
    int mrow = m0 + row; if (mrow >= M) mrow = M - 1;
    size_t off = (size_t)mrow * 256 + c0;
    float4 ld[8];
#pragma unroll
    for (int j = 0; j < 8; ++j) {
      float4 x = *(const float4*)(p0 + off + j * 4);
      float4 y = *(const float4*)(p1 + off + j * 4);
      x.x += y.x; x.y += y.y; x.z += y.z; x.w += y.w;
      ld[j] = x;
    }
    short* dst = &As[sub][row * 264 + c0];
#pragma unroll
    for (int j = 0; j < 4; ++j)
      *(short8v*)(dst + j * 8) = pack8(ld[2 * j], ld[2 * j + 1]);
  }
  __syncthreads();

  f32x4 acc[2][4] = {};
  const short* wbase = Wp + (size_t)(wave * 64 + r) * 256;
#pragma unroll
  for (int ks = 0; ks < 8; ++ks) {
    short8v af0 = *(const short8v*)&As[sub][r * 264 + ks * 32 + g * 8];
    short8v af1 = *(const short8v*)&As[sub][(16 + r) * 264 + ks * 32 + g * 8];
    short8v bfr[4];
#pragma unroll
    for (int nf = 0; nf < 4; ++nf)
      bfr[nf] = *(const short8v*)(wbase + nf * 16 * 256 + ks * 32 + g * 8);
#pragma unroll
    for (int nf = 0; nf < 4; ++nf) {
      acc[0][nf] = __builtin_amdgcn_mfma_f32_16x16x32_bf16(af0, bfr[nf], acc[0][nf], 0, 0, 0);
      acc[1][nf] = __builtin_amdgcn_mfma_f32_16x16x32_bf16(af1, bfr[nf], acc[1][nf], 0, 0, 0);
    }
  }

#pragma unroll
  for (int mf = 0; mf < 2; ++mf)
#pragma unroll
    for (int nf = 0; nf < 4; ++nf) {
      int nn = wave * 64 + nf * 16 + r;
      float bval = bp[nn];
#pragma unroll
      for (int i = 0; i < 4; ++i) {
        int m = m0 + mf * 16 + g * 4 + i;
        if (m >= M) continue;
        int bb = m / 300, ll = m - bb * 300;
        Cf[((size_t)ll * 8 + bb) * 256 + nn] = acc[mf][nf][i] + bval;
      }
    }
}

// ---------------- scores + softmax: MFMA + in-register softmax ----------------
__global__ __launch_bounds__(64) void scores_softmax_v2(
    const short* __restrict__ qrb, const short* __restrict__ qcb,
    const short* __restrict__ krb, const short* __restrict__ kcb,
    short* __restrict__ wrowB, float* __restrict__ wcolT) {
  int lchunk = blockIdx.x, bn = blockIdx.y, kind = blockIdx.z;
  int b = bn >> 3, n = bn & 7;
  int lane = threadIdx.x;
  int r = lane & 15, g = lane >> 4;
  const short* qb = kind ? qcb : qrb;
  const short* kb = kind ? kcb : krb;
  int l0 = lchunk * 80;

  short8v a[5], bfr[6];
#pragma unroll
  for (int lf = 0; lf < 5; ++lf) {
    int l = l0 + lf * 16 + r;
    if (l > 299) l = 299;
    a[lf] = *(const short8v*)(qb + ((size_t)b * 300 + l) * 256 + n * 32 + g * 8);
  }
#pragma unroll
  for (int f = 0; f < 6; ++f)
    bfr[f] = *(const short8v*)(kb + ((size_t)b * 96 + f * 16 + r) * 256 + n * 32 + g * 8);

  f32x4 c[5][6];
#pragma unroll
  for (int lf = 0; lf < 5; ++lf)
#pragma unroll
    for (int f = 0; f < 6; ++f) {
      f32x4 z = {};
      c[lf][f] = __builtin_amdgcn_mfma_f32_16x16x32_bf16(a[lf], bfr[f], z, 0, 0, 0);
    }

#pragma unroll
  for (int lf = 0; lf < 5; ++lf)
#pragma unroll
    for (int i = 0; i < 4; ++i) {
      float m = c[lf][0][i];
#pragma unroll
      for (int f = 1; f < 6; ++f) m = fmaxf(m, c[lf][f][i]);
#pragma unroll
      for (int mask = 1; mask <= 8; mask <<= 1) m = fmaxf(m, __shfl_xor(m, mask, 64));
      float e[6], s = 0.f;
#pragma unroll
      for (int f = 0; f < 6; ++f) { e[f] = __expf(c[lf][f][i] - m); s += e[f]; }
#pragma unroll
      for (int mask = 1; mask <= 8; mask <<= 1) s += __shfl_xor(s, mask, 64);
      float inv = 1.f / s;
#pragma unroll
      for (int f = 0; f < 6; ++f) c[lf][f][i] = e[f] * inv;
    }

  if (kind == 0) {
#pragma unroll
    for (int lf = 0; lf < 5; ++lf)
#pragma unroll
      for (int i = 0; i < 4; ++i) {
        int l = l0 + lf * 16 + g * 4 + i;
        bool ok = (l < 300);
#pragma unroll
        for (int f = 0; f < 6; ++f) {
          float wv = ok ? c[lf][f][i] : 0.f;
          wrowB[((size_t)bn * 320 + l) * 96 + f * 16 + r] = (short)f2bf(wv);
        }
      }
  } else {
#pragma unroll
    for (int lf = 0; lf < 5; ++lf)
#pragma unroll
      for (int f = 0; f < 6; ++f) {
        int l = l0 + lf * 16 + g * 4;
        f32x4 wv = c[lf][f];
#pragma unroll
        for (int i = 0; i < 4; ++i) if (l + i >= 300) wv[i] = 0.f;
        *(f32x4*)(wcolT + ((size_t)bn * 96 + f * 16 + r) * 320 + l) = wv;
      }
  }
}

// ---------------- fused bilinear attention (r16: h split x2) ----------
__global__ __launch_bounds__(512, 2) void attn_kernel(
    const short* __restrict__ wrowB, const float* __restrict__ wcolT,
    const short* __restrict__ vvT, float* __restrict__ part0,
    float* __restrict__ part1) {
  __shared__ f32x4 cmb[3][2][4][64];
  int i = blockIdx.x;
  int xcd = i & 7, j = i >> 3;          // j 0..79
  int grp = j / 10, rem = j - grp * 10;
  int bn = grp * 8 + xcd;               // all 10 blocks of a bn -> same XCD
  int lh = rem >> 1, hh2 = rem & 1;
  int b = bn >> 3, n = bn & 7;
  int t = threadIdx.x, wave = t >> 6, lane = t & 63;
  int df = wave & 1, hq = wave >> 1;    // hq 0..3, 12 h each
  int lbase = lh * 64;
  int r = lane & 15, g = lane >> 4;
  int hbase = hh2 * 48 + hq * 12;

  short8v a[4][3];
  const short* wr = wrowB + (size_t)bn * 320 * 96;
#pragma unroll
  for (int lf = 0; lf < 4; ++lf)
#pragma unroll
    for (int ks = 0; ks < 3; ++ks)
      a[lf][ks] = *(const short8v*)(wr + (lbase + lf * 16 + r) * 96 + ks * 32 + g * 8);

  const short* vb = vvT + (size_t)bn * 294912 + (size_t)(df * 16 + r) * 9216 + hbase * 96;
  const float* wcb = wcolT + ((size_t)bn * 96 + hbase) * 320 + lbase + g * 4;

  f32x4 acc[4] = {};
  short8v b0[3], b1[3];
  f32x4 w0[4], w1[4];
#pragma unroll
  for (int ks = 0; ks < 3; ++ks) b0[ks] = *(const short8v*)(vb + ks * 32 + g * 8);
#pragma unroll
  for (int lf = 0; lf < 4; ++lf) w0[lf] = *(const f32x4*)(wcb + lf * 16);

#pragma unroll
  for (int h2 = 0; h2 < 6; ++h2) {
    int h = h2 * 2;
#pragma unroll
    for (int ks = 0; ks < 3; ++ks) b1[ks] = *(const short8v*)(vb + (h + 1) * 96 + ks * 32 + g * 8);
#pragma unroll
    for (int lf = 0; lf < 4; ++lf) w1[lf] = *(const f32x4*)(wcb + (h + 1) * 320 + lf * 16);
    {
      f32x4 R[4] = {};
#pragma unroll
      for (int ks = 0; ks < 3; ++ks)
#pragma unroll
        for (int lf = 0; lf < 4; ++lf)
          R[lf] = __builtin_amdgcn_mfma_f32_16x16x32_bf16(a[lf][ks], b0[ks], R[lf], 0, 0, 0);
#pragma unroll
      for (int lf = 0; lf < 4; ++lf) acc[lf] += w0[lf] * R[lf];
    }
    if (h2 < 5) {
#pragma unroll
      for (int ks = 0; ks < 3; ++ks) b0[ks] = *(const short8v*)(vb + (h + 2) * 96 + ks * 32 + g * 8);
#pragma unroll
      for (int lf = 0; lf < 4; ++lf) w0[lf] = *(const f32x4*)(wcb + (h + 2) * 320 + lf * 16);
    }
    {
      f32x4 R[4] = {};
#pragma unroll
      for (int ks = 0; ks < 3; ++ks)
#pragma unroll
        for (int lf = 0; lf < 4; ++lf)
          R[lf] = __builtin_amdgcn_mfma_f32_16x16x32_bf16(a[lf][ks], b1[ks], R[lf], 0, 0, 0);
#pragma unroll
      for (int lf = 0; lf < 4; ++lf) acc[lf] += w1[lf] * R[lf];
    }
  }

  if (hq > 0) {
#pragma unroll
    for (int lf = 0; lf < 4; ++lf) cmb[hq - 1][df][lf][lane] = acc[lf];
  }
  __syncthreads();
  if (hq == 0) {
    float* po = hh2 ? part1 : part0;
#pragma unroll
    for (int lf = 0; lf < 4; ++lf) {
      f32x4 o = acc[lf];
#pragma unroll
      for (int q = 0; q < 3; ++q) o += cmb[q][df][lf][lane];
#pragma unroll
      for (int i2 = 0; i2 < 4; ++i2) {
        int l = lbase + lf * 16 + g * 4 + i2;
        if (l < 300)
          po[((size_t)b * 300 + l) * 256 + n * 32 + df * 16 + r] = o[i2];
      }
    }
  }
}

// ---------------- launch ----------------
extern "C" void kernel_launch(void* const* d_in, const int* in_sizes, int n_in,
                              void* d_out, int out_size, void* d_ws, size_t ws_size,
                              hipStream_t stream) {
  const float* query_row = (const float*)d_in[0];
  const float* query_col = (const float*)d_in[1];
  const float* key_row   = (const float*)d_in[2];
  const float* key_col   = (const float*)d_in[3];
  const float* value     = (const float*)d_in[4];
  const float* W         = (const float*)d_in[5];  // (1280,256)
  const float* Bv        = (const float*)d_in[6];  // (1280,)
  const float* Wout      = (const float*)d_in[7];  // (256,256)
  const float* Bout      = (const float*)d_in[8];  // (256,)

  float* ws = (float*)d_ws;
  float* krm   = ws;                        // 196608 f
  float* kcm   = krm + 196608;              // 196608 f
  float* part0 = kcm + 196608;              // 614400 f
  float* part1 = part0 + 614400;            // 614400 f
  float* wcolT = part1 + 614400;            // 1966080 f
  short* qrb   = (short*)(wcolT + 1966080); // 614400 s
  short* qcb   = qrb + 614400;              // 614400 s
  short* krb   = qcb + 614400;              // 196608 s
  short* kcb   = krb + 196608;              // 196608 s
  short* wrowB = kcb + 196608;              // 1966080 s
  short* vvT   = wrowB + 1966080;           // 18874368 s
  short* Wb    = vvT + 18874368;            // 393216 s

  cvt_w_kernel<<<1536, 256, 0, stream>>>(W, Wout, Wb);
  mean_over_h_v3<<<768, 256, 0, stream>>>(key_row, krm);
  mean_over_w_v3<<<768, 256, 0, stream>>>(key_col, kcm);
  vproj_kernel<<<768, 512, 0, stream>>>(value, Wb + 262144, Bv + 1024, vvT);
  gemm512<<<100, 512, 0, stream>>>(krm, kcm, query_row, query_col, Wb, Bv,
                                   krb, kcb, qrb, qcb);
  scores_softmax_v2<<<dim3(4, 64, 2), 64, 0, stream>>>(qrb, qcb, krb, kcb, wrowB, wcolT);
  attn_kernel<<<640, 512, 0, stream>>>(wrowB, wcolT, vvT, part0, part1);
  gemm512_out<<<38, 512, 0, stream>>>(part0, part1, Wb + 327680, Bout, (float*)d_out);
}

// Round 20
// 139.869 us; speedup vs baseline: 2.1883x; 1.1300x over previous
//
#include <hip/hip_runtime.h>
#include <cstdint>

// MultiheadRCDA: N=8, L=300, HH=WW=96, E=256, NH=8, HD=32
// Round 20: attn v5 — wcolT staged in LDS per block (12KB; per-h-step global
// chain drops 112B->48B/lane; wc dedup 30->7.9MB). cvt_w folded into mean_h
// tail (one fewer launch). All else = r19 (proven pieces).

typedef __attribute__((ext_vector_type(8))) short short8v;  // bf16x8 MFMA frag
typedef __attribute__((ext_vector_type(4))) short short4v;  // 8B packed bf16
typedef __attribute__((ext_vector_type(4))) float f32x4;

#define SCALE_Q 0.17677669529663687f  // 32^-0.5

#define GLL16(gp, lp)                                                   \
  __builtin_amdgcn_global_load_lds(                                     \
      (const __attribute__((address_space(1))) void*)(gp),              \
      (__attribute__((address_space(3))) void*)(lp), 16, 0, 0)

__device__ __forceinline__ unsigned short f2bf(float x) {
  unsigned int u = __builtin_bit_cast(unsigned int, x);
  u += 0x7FFFu + ((u >> 16) & 1u);
  return (unsigned short)(u >> 16);
}

__device__ __forceinline__ unsigned int cvtpk(float a, float b) {
  unsigned int r;
  asm("v_cvt_pk_bf16_f32 %0, %1, %2" : "=v"(r) : "v"(a), "v"(b));
  return r;
}

__device__ __forceinline__ short8v pack8cvt(const f32x4& lo, const f32x4& hi) {
  union { short8v s; unsigned int u[4]; } z;
  z.u[0] = cvtpk(lo[0], lo[1]);
  z.u[1] = cvtpk(lo[2], lo[3]);
  z.u[2] = cvtpk(hi[0], hi[1]);
  z.u[3] = cvtpk(hi[2], hi[3]);
  return z.s;
}

__device__ __forceinline__ short4v pack4cvt(float a, float b, float c, float d) {
  union { short4v s; unsigned int u[2]; } z;
  z.u[0] = cvtpk(a, b);
  z.u[1] = cvtpk(c, d);
  return z.s;
}

__device__ __forceinline__ short8v pack8(const float4& fa, const float4& fb) {
  short8v v;
  v[0] = (short)f2bf(fa.x); v[1] = (short)f2bf(fa.y);
  v[2] = (short)f2bf(fa.z); v[3] = (short)f2bf(fa.w);
  v[4] = (short)f2bf(fb.x); v[5] = (short)f2bf(fb.y);
  v[6] = (short)f2bf(fb.z); v[7] = (short)f2bf(fb.w);
  return v;
}

// ---------------- mean_h + weight-convert tail ----------------
__global__ __launch_bounds__(256) void mean_over_h_v3(const float* __restrict__ in,
                                                      float* __restrict__ out,
                                                      const float* __restrict__ w_in,
                                                      const float* __restrict__ w_out,
                                                      short* __restrict__ Wb) {
  __shared__ float4 part[256];
  int bw = blockIdx.x;  // b*96 + w
  int b = bw / 96, w = bw - b * 96;
  int t = threadIdx.x, e4 = t & 63, hq = t >> 6;
  const float4* p = (const float4*)(in + ((size_t)b * 9216 + w) * 256) + e4 +
                    (size_t)hq * 24 * 6144;
  float4 s = {0.f, 0.f, 0.f, 0.f};
#pragma unroll
  for (int i = 0; i < 24; ++i) {
    float4 v = p[(size_t)i * 6144];
    s.x += v.x; s.y += v.y; s.z += v.z; s.w += v.w;
  }
  part[t] = s;
  __syncthreads();
  if (t < 64) {
    float4 a = part[t], c = part[t + 64], d = part[t + 128], e = part[t + 192];
    float4 o;
    o.x = (a.x + c.x + d.x + e.x) * (1.f / 96.f);
    o.y = (a.y + c.y + d.y + e.y) * (1.f / 96.f);
    o.z = (a.z + c.z + d.z + e.z) * (1.f / 96.f);
    o.w = (a.w + c.w + d.w + e.w) * (1.f / 96.f);
    ((float4*)out)[(size_t)bw * 64 + t] = o;
  }
  // tail: convert 512 weight elems per block (768*512 = 393216)
#pragma unroll
  for (int k = 0; k < 2; ++k) {
    int idx = blockIdx.x * 512 + k * 256 + t;
    float v = (idx < 327680) ? w_in[idx] : w_out[idx - 327680];
    Wb[idx] = (short)f2bf(v);
  }
}

__global__ __launch_bounds__(256) void mean_over_w_v3(const float* __restrict__ in,
                                                      float* __restrict__ out) {
  __shared__ float4 part[256];
  int bh = blockIdx.x;  // b*96 + h
  int t = threadIdx.x, e4 = t & 63, wq = t >> 6;
  const float4* p = (const float4*)(in + (size_t)bh * 24576) + e4 + (size_t)wq * 24 * 64;
  float4 s = {0.f, 0.f, 0.f, 0.f};
#pragma unroll
  for (int i = 0; i < 24; ++i) {
    float4 v = p[(size_t)i * 64];
    s.x += v.x; s.y += v.y; s.z += v.z; s.w += v.w;
  }
  part[t] = s;
  __syncthreads();
  if (t < 64) {
    float4 a = part[t], c = part[t + 64], d = part[t + 128], e = part[t + 192];
    float4 o;
    o.x = (a.x + c.x + d.x + e.x) * (1.f / 96.f);
    o.y = (a.y + c.y + d.y + e.y) * (1.f / 96.f);
    o.z = (a.z + c.z + d.z + e.z) * (1.f / 96.f);
    o.w = (a.w + c.w + d.w + e.w) * (1.f / 96.f);
    ((float4*)out)[(size_t)bh * 64 + t] = o;
  }
}

// ---------------- value projection (r16: 3 blocks/CU) ----------------
__global__ __launch_bounds__(512, 4) void vproj_kernel(
    const float* __restrict__ A, const short* __restrict__ Wb,
    const float* __restrict__ bias, short* __restrict__ vvT) {
  __shared__ float buf[2][16 * 260];   // 33.3 KB
  __shared__ short Ts[8][32 * 36];     // 18.4 KB
  int t = threadIdx.x;
  int wave = t >> 6, lane = t & 63, r = lane & 15, g = lane >> 4;
  int m0g = blockIdx.x * 96;
  int b_ = blockIdx.x / 96;
  int hw00 = (blockIdx.x - b_ * 96) * 96;
  int chbase = wave * 32;

  short8v bf[8][2];
  {
    const short* wbase = Wb + (size_t)(chbase + r) * 256;
#pragma unroll
    for (int ks = 0; ks < 8; ++ks)
#pragma unroll
      for (int nf = 0; nf < 2; ++nf)
        bf[ks][nf] = *(const short8v*)(wbase + nf * 16 * 256 + ks * 32 + g * 8);
  }
#pragma unroll
  for (int ks = 0; ks < 8; ++ks)
#pragma unroll
    for (int nf = 0; nf < 2; ++nf)
      asm volatile("" : "+a"(bf[ks][nf]));
  float bias_v[2];
#pragma unroll
  for (int nf = 0; nf < 2; ++nf) bias_v[nf] = bias[chbase + nf * 16 + r];

#pragma unroll
  for (int q = 0; q < 2; ++q) {
#pragma unroll
    for (int i = 0; i < 2; ++i) {
      int row = wave * 2 + i;
      const float* gp = A + ((size_t)m0g + q * 16 + row) * 256 + lane * 4;
      GLL16(gp, &buf[q][row * 260]);
    }
  }

  int chg = chbase + (lane & 31);
  int half = lane >> 5;
  short* vbase = vvT + (size_t)(b_ * 8 + (chg >> 5)) * 294912 +
                 (size_t)(chg & 31) * 9216 + hw00;
  const short* tsr = &Ts[wave][(lane & 31) * 36];

#pragma unroll
  for (int tt = 0; tt < 6; ++tt) {
    if (tt == 5)                  asm volatile("s_waitcnt vmcnt(0)" ::: "memory");
    else if (tt == 2 || tt == 4)  asm volatile("s_waitcnt vmcnt(4)" ::: "memory");
    else                          asm volatile("s_waitcnt vmcnt(2)" ::: "memory");
    __builtin_amdgcn_s_barrier();

    f32x4 acc[2] = {};
    const float* bp_ = &buf[tt & 1][0];
#pragma unroll
    for (int ks = 0; ks < 8; ++ks) {
      const float* p = bp_ + r * 260 + ks * 32 + g * 8;
      f32x4 lo = *(const f32x4*)p;
      f32x4 hi = *(const f32x4*)(p + 4);
      short8v af = pack8cvt(lo, hi);
      acc[0] = __builtin_amdgcn_mfma_f32_16x16x32_bf16(af, bf[ks][0], acc[0], 0, 0, 0);
      acc[1] = __builtin_amdgcn_mfma_f32_16x16x32_bf16(af, bf[ks][1], acc[1], 0, 0, 0);
    }

#pragma unroll
    for (int nf = 0; nf < 2; ++nf) {
      float bv = bias_v[nf];
      *(short4v*)&Ts[wave][(nf * 16 + r) * 36 + (tt & 1) * 16 + g * 4] =
          pack4cvt(acc[nf][0] + bv, acc[nf][1] + bv, acc[nf][2] + bv, acc[nf][3] + bv);
    }
    asm volatile("" ::: "memory");

    if (tt & 1) {
      short* gdst = vbase + (tt - 1) * 16 + half * 16;
      const short* src = tsr + half * 16;
      *(short8v*)gdst = *(const short8v*)src;
      *(short8v*)(gdst + 8) = *(const short8v*)(src + 8);
      asm volatile("" ::: "memory");
    }

    __builtin_amdgcn_s_barrier();
    if (tt + 2 < 6) {
#pragma unroll
      for (int i = 0; i < 2; ++i) {
        int row = wave * 2 + i;
        const float* gp = A + ((size_t)m0g + (tt + 2) * 16 + row) * 256 + lane * 4;
        GLL16(gp, &buf[tt & 1][row * 260]);
      }
    }
  }
}

// ---------------- gemm512: kproj + qproj in one launch ----------------
__global__ __launch_bounds__(512) void gemm512(
    const float* __restrict__ krm, const float* __restrict__ kcm,
    const float* __restrict__ qrow, const float* __restrict__ qcol,
    const short* __restrict__ Wb, const float* __restrict__ Bv,
    short* __restrict__ krb, short* __restrict__ kcb,
    short* __restrict__ qrb, short* __restrict__ qcb) {
  __shared__ short As[2][32 * 264];
  int id = blockIdx.x;
  const float* A; short* Cb; const short* Wp; const float* bp; int M, m064;
  float scale;
  if (id < 12)      { A = krm;  Cb = krb; Wp = Wb + 131072; bp = Bv + 512; M = 768;  m064 = id * 64;        scale = 1.f; }
  else if (id < 24) { A = kcm;  Cb = kcb; Wp = Wb + 196608; bp = Bv + 768; M = 768;  m064 = (id - 12) * 64; scale = 1.f; }
  else if (id < 62) { A = qrow; Cb = qrb; Wp = Wb;          bp = Bv;       M = 2400; m064 = (id - 24) * 64; scale = SCALE_Q; }
  else              { A = qcol; Cb = qcb; Wp = Wb + 65536;  bp = Bv + 256; M = 2400; m064 = (id - 62) * 64; scale = SCALE_Q; }

  int t = threadIdx.x, sub = t >> 8, u = t & 255;
  int wave = u >> 6, lane = u & 63, r = lane & 15, g = lane >> 4;
  int m0 = m064 + sub * 32;

  {
    int row = u >> 3, c0 = (u & 7) * 32;
    int mrow = m0 + row; if (mrow >= M) mrow = M - 1;
    const float* ap = A + (size_t)mrow * 256 + c0;
    float4 ld[8];
#pragma unroll
    for (int j = 0; j < 8; ++j) ld[j] = *(const float4*)(ap + j * 4);
    short* dst = &As[sub][row * 264 + c0];
#pragma unroll
    for (int j = 0; j < 4; ++j)
      *(short8v*)(dst + j * 8) = pack8(ld[2 * j], ld[2 * j + 1]);
  }
  __syncthreads();

  f32x4 acc[2][4] = {};
  const short* wbase = Wp + (size_t)(wave * 64 + r) * 256;
#pragma unroll
  for (int ks = 0; ks < 8; ++ks) {
    short8v af0 = *(const short8v*)&As[sub][r * 264 + ks * 32 + g * 8];
    short8v af1 = *(const short8v*)&As[sub][(16 + r) * 264 + ks * 32 + g * 8];
    short8v bfr[4];
#pragma unroll
    for (int nf = 0; nf < 4; ++nf)
      bfr[nf] = *(const short8v*)(wbase + nf * 16 * 256 + ks * 32 + g * 8);
#pragma unroll
    for (int nf = 0; nf < 4; ++nf) {
      acc[0][nf] = __builtin_amdgcn_mfma_f32_16x16x32_bf16(af0, bfr[nf], acc[0][nf], 0, 0, 0);
      acc[1][nf] = __builtin_amdgcn_mfma_f32_16x16x32_bf16(af1, bfr[nf], acc[1][nf], 0, 0, 0);
    }
  }

#pragma unroll
  for (int mf = 0; mf < 2; ++mf)
#pragma unroll
    for (int nf = 0; nf < 4; ++nf) {
      int nn = wave * 64 + nf * 16 + r;
      float bval = bp[nn];
#pragma unroll
      for (int i = 0; i < 4; ++i) {
        int m = m0 + mf * 16 + g * 4 + i;
        if (m >= M) continue;
        Cb[(size_t)m * 256 + nn] = (short)f2bf((acc[mf][nf][i] + bval) * scale);
      }
    }
}

// ---------------- out-projection: (part0+part1) @ Wout^T + Bout ----------------
__global__ __launch_bounds__(512) void gemm512_out(
    const float* __restrict__ p0, const float* __restrict__ p1,
    const short* __restrict__ Wp, const float* __restrict__ bp,
    float* __restrict__ Cf) {
  __shared__ short As[2][32 * 264];
  const int M = 2400;
  int t = threadIdx.x, sub = t >> 8, u = t & 255;
  int wave = u >> 6, lane = u & 63, r = lane & 15, g = lane >> 4;
  int m0 = blockIdx.x * 64 + sub * 32;

  {
    int row = u >> 3, c0 = (u & 7) * 32;
    int mrow = m0 + row; if (mrow >= M) mrow = M - 1;
    size_t off = (size_t)mrow * 256 + c0;
    float4 ld[8];
#pragma unroll
    for (int j = 0; j < 8; ++j) {
      float4 x = *(const float4*)(p0 + off + j * 4);
      float4 y = *(const float4*)(p1 + off + j * 4);
      x.x += y.x; x.y += y.y; x.z += y.z; x.w += y.w;
      ld[j] = x;
    }
    short* dst = &As[sub][row * 264 + c0];
#pragma unroll
    for (int j = 0; j < 4; ++j)
      *(short8v*)(dst + j * 8) = pack8(ld[2 * j], ld[2 * j + 1]);
  }
  __syncthreads();

  f32x4 acc[2][4] = {};
  const short* wbase = Wp + (size_t)(wave * 64 + r) * 256;
#pragma unroll
  for (int ks = 0; ks < 8; ++ks) {
    short8v af0 = *(const short8v*)&As[sub][r * 264 + ks * 32 + g * 8];
    short8v af1 = *(const short8v*)&As[sub][(16 + r) * 264 + ks * 32 + g * 8];
    short8v bfr[4];
#pragma unroll
    for (int nf = 0; nf < 4; ++nf)
      bfr[nf] = *(const short8v*)(wbase + nf * 16 * 256 + ks * 32 + g * 8);
#pragma unroll
    for (int nf = 0; nf < 4; ++nf) {
      acc[0][nf] = __builtin_amdgcn_mfma_f32_16x16x32_bf16(af0, bfr[nf], acc[0][nf], 0, 0, 0);
      acc[1][nf] = __builtin_amdgcn_mfma_f32_16x16x32_bf16(af1, bfr[nf], acc[1][nf], 0, 0, 0);
    }
  }

#pragma unroll
  for (int mf = 0; mf < 2; ++mf)
#pragma unroll
    for (int nf = 0; nf < 4; ++nf) {
      int nn = wave * 64 + nf * 16 + r;
      float bval = bp[nn];
#pragma unroll
      for (int i = 0; i < 4; ++i) {
        int m = m0 + mf * 16 + g * 4 + i;
        if (m >= M) continue;
        int bb = m / 300, ll = m - bb * 300;
        Cf[((size_t)ll * 8 + bb) * 256 + nn] = acc[mf][nf][i] + bval;
      }
    }
}

// ---------------- scores + softmax: MFMA + in-register softmax ----------------
__global__ __launch_bounds__(64) void scores_softmax_v2(
    const short* __restrict__ qrb, const short* __restrict__ qcb,
    const short* __restrict__ krb, const short* __restrict__ kcb,
    short* __restrict__ wrowB, float* __restrict__ wcolT) {
  int lchunk = blockIdx.x, bn = blockIdx.y, kind = blockIdx.z;
  int b = bn >> 3, n = bn & 7;
  int lane = threadIdx.x;
  int r = lane & 15, g = lane >> 4;
  const short* qb = kind ? qcb : qrb;
  const short* kb = kind ? kcb : krb;
  int l0 = lchunk * 80;

  short8v a[5], bfr[6];
#pragma unroll
  for (int lf = 0; lf < 5; ++lf) {
    int l = l0 + lf * 16 + r;
    if (l > 299) l = 299;
    a[lf] = *(const short8v*)(qb + ((size_t)b * 300 + l) * 256 + n * 32 + g * 8);
  }
#pragma unroll
  for (int f = 0; f < 6; ++f)
    bfr[f] = *(const short8v*)(kb + ((size_t)b * 96 + f * 16 + r) * 256 + n * 32 + g * 8);

  f32x4 c[5][6];
#pragma unroll
  for (int lf = 0; lf < 5; ++lf)
#pragma unroll
    for (int f = 0; f < 6; ++f) {
      f32x4 z = {};
      c[lf][f] = __builtin_amdgcn_mfma_f32_16x16x32_bf16(a[lf], bfr[f], z, 0, 0, 0);
    }

#pragma unroll
  for (int lf = 0; lf < 5; ++lf)
#pragma unroll
    for (int i = 0; i < 4; ++i) {
      float m = c[lf][0][i];
#pragma unroll
      for (int f = 1; f < 6; ++f) m = fmaxf(m, c[lf][f][i]);
#pragma unroll
      for (int mask = 1; mask <= 8; mask <<= 1) m = fmaxf(m, __shfl_xor(m, mask, 64));
      float e[6], s = 0.f;
#pragma unroll
      for (int f = 0; f < 6; ++f) { e[f] = __expf(c[lf][f][i] - m); s += e[f]; }
#pragma unroll
      for (int mask = 1; mask <= 8; mask <<= 1) s += __shfl_xor(s, mask, 64);
      float inv = 1.f / s;
#pragma unroll
      for (int f = 0; f < 6; ++f) c[lf][f][i] = e[f] * inv;
    }

  if (kind == 0) {
#pragma unroll
    for (int lf = 0; lf < 5; ++lf)
#pragma unroll
      for (int i = 0; i < 4; ++i) {
        int l = l0 + lf * 16 + g * 4 + i;
        bool ok = (l < 300);
#pragma unroll
        for (int f = 0; f < 6; ++f) {
          float wv = ok ? c[lf][f][i] : 0.f;
          wrowB[((size_t)bn * 320 + l) * 96 + f * 16 + r] = (short)f2bf(wv);
        }
      }
  } else {
#pragma unroll
    for (int lf = 0; lf < 5; ++lf)
#pragma unroll
      for (int f = 0; f < 6; ++f) {
        int l = l0 + lf * 16 + g * 4;
        f32x4 wv = c[lf][f];
#pragma unroll
        for (int i = 0; i < 4; ++i) if (l + i >= 300) wv[i] = 0.f;
        *(f32x4*)(wcolT + ((size_t)bn * 96 + f * 16 + r) * 320 + l) = wv;
      }
  }
}

// ---------------- attention v5: r16 h-split + wcolT LDS-staged ----------
__global__ __launch_bounds__(512, 2) void attn_kernel(
    const short* __restrict__ wrowB, const float* __restrict__ wcolT,
    const short* __restrict__ vvT, float* __restrict__ part0,
    float* __restrict__ part1) {
  __shared__ f32x4 cmb[3][2][4][64];  // 24.6 KB
  __shared__ float wcs[48][64];       // 12.3 KB
  int i = blockIdx.x;
  int xcd = i & 7, j = i >> 3;          // j 0..79
  int grp = j / 10, rem = j - grp * 10;
  int bn = grp * 8 + xcd;               // all 10 blocks of a bn -> same XCD
  int lh = rem >> 1, hh2 = rem & 1;
  int b = bn >> 3, n = bn & 7;
  int t = threadIdx.x, wave = t >> 6, lane = t & 63;
  int df = wave & 1, hq = wave >> 1;    // hq 0..3, 12 h each
  int lbase = lh * 64;
  int r = lane & 15, g = lane >> 4;
  int hbase = hh2 * 48 + hq * 12;

  // stage wc slice (48 h x 64 l) once per block: 768 f32x4 units
  {
    const float* wsrc = wcolT + ((size_t)bn * 96 + hh2 * 48) * 320 + lbase;
#pragma unroll
    for (int k = 0; k < 2; ++k) {
      int u = t + k * 512;  // 0..1023; use first 768
      if (u < 768) {
        int row = u >> 4, cb = (u & 15) * 4;
        *(f32x4*)&wcs[row][cb] = *(const f32x4*)(wsrc + row * 320 + cb);
      }
    }
  }

  short8v a[4][3];
  const short* wr = wrowB + (size_t)bn * 320 * 96;
#pragma unroll
  for (int lf = 0; lf < 4; ++lf)
#pragma unroll
    for (int ks = 0; ks < 3; ++ks)
      a[lf][ks] = *(const short8v*)(wr + (lbase + lf * 16 + r) * 96 + ks * 32 + g * 8);

  const short* vb = vvT + (size_t)bn * 294912 + (size_t)(df * 16 + r) * 9216 + hbase * 96;
  __syncthreads();  // wcs ready

  f32x4 acc[4] = {};
  short8v b0[3], b1[3];
  int hl = hq * 12;  // local h row base in wcs
#pragma unroll
  for (int ks = 0; ks < 3; ++ks) b0[ks] = *(const short8v*)(vb + ks * 32 + g * 8);

#pragma unroll
  for (int h2 = 0; h2 < 6; ++h2) {
    int h = h2 * 2;
#pragma unroll
    for (int ks = 0; ks < 3; ++ks) b1[ks] = *(const short8v*)(vb + (h + 1) * 96 + ks * 32 + g * 8);
    {
      f32x4 R[4] = {};
#pragma unroll
      for (int ks = 0; ks < 3; ++ks)
#pragma unroll
        for (int lf = 0; lf < 4; ++lf)
          R[lf] = __builtin_amdgcn_mfma_f32_16x16x32_bf16(a[lf][ks], b0[ks], R[lf], 0, 0, 0);
#pragma unroll
      for (int lf = 0; lf < 4; ++lf) {
        f32x4 w = *(const f32x4*)&wcs[hl + h][lf * 16 + g * 4];
        acc[lf] += w * R[lf];
      }
    }
    if (h2 < 5) {
#pragma unroll
      for (int ks = 0; ks < 3; ++ks) b0[ks] = *(const short8v*)(vb + (h + 2) * 96 + ks * 32 + g * 8);
    }
    {
      f32x4 R[4] = {};
#pragma unroll
      for (int ks = 0; ks < 3; ++ks)
#pragma unroll
        for (int lf = 0; lf < 4; ++lf)
          R[lf] = __builtin_amdgcn_mfma_f32_16x16x32_bf16(a[lf][ks], b1[ks], R[lf], 0, 0, 0);
#pragma unroll
      for (int lf = 0; lf < 4; ++lf) {
        f32x4 w = *(const f32x4*)&wcs[hl + h + 1][lf * 16 + g * 4];
        acc[lf] += w * R[lf];
      }
    }
  }

  if (hq > 0) {
#pragma unroll
    for (int lf = 0; lf < 4; ++lf) cmb[hq - 1][df][lf][lane] = acc[lf];
  }
  __syncthreads();
  if (hq == 0) {
    float* po = hh2 ? part1 : part0;
#pragma unroll
    for (int lf = 0; lf < 4; ++lf) {
      f32x4 o = acc[lf];
#pragma unroll
      for (int q = 0; q < 3; ++q) o += cmb[q][df][lf][lane];
#pragma unroll
      for (int i2 = 0; i2 < 4; ++i2) {
        int l = lbase + lf * 16 + g * 4 + i2;
        if (l < 300)
          po[((size_t)b * 300 + l) * 256 + n * 32 + df * 16 + r] = o[i2];
      }
    }
  }
}

// ---------------- launch ----------------
extern "C" void kernel_launch(void* const* d_in, const int* in_sizes, int n_in,
                              void* d_out, int out_size, void* d_ws, size_t ws_size,
                              hipStream_t stream) {
  const float* query_row = (const float*)d_in[0];
  const float* query_col = (const float*)d_in[1];
  const float* key_row   = (const float*)d_in[2];
  const float* key_col   = (const float*)d_in[3];
  const float* value     = (const float*)d_in[4];
  const float* W         = (const float*)d_in[5];  // (1280,256)
  const float* Bv        = (const float*)d_in[6];  // (1280,)
  const float* Wout      = (const float*)d_in[7];  // (256,256)
  const float* Bout      = (const float*)d_in[8];  // (256,)

  float* ws = (float*)d_ws;
  float* krm   = ws;                        // 196608 f
  float* kcm   = krm + 196608;              // 196608 f
  float* part0 = kcm + 196608;              // 614400 f
  float* part1 = part0 + 614400;            // 614400 f
  float* wcolT = part1 + 614400;            // 1966080 f
  short* qrb   = (short*)(wcolT + 1966080); // 614400 s
  short* qcb   = qrb + 614400;              // 614400 s
  short* krb   = qcb + 614400;              // 196608 s
  short* kcb   = krb + 196608;              // 196608 s
  short* wrowB = kcb + 196608;              // 1966080 s
  short* vvT   = wrowB + 1966080;           // 18874368 s
  short* Wb    = vvT + 18874368;            // 393216 s

  mean_over_h_v3<<<768, 256, 0, stream>>>(key_row, krm, W, Wout, Wb);
  mean_over_w_v3<<<768, 256, 0, stream>>>(key_col, kcm);
  vproj_kernel<<<768, 512, 0, stream>>>(value, Wb + 262144, Bv + 1024, vvT);
  gemm512<<<100, 512, 0, stream>>>(krm, kcm, query_row, query_col, Wb, Bv,
                                   krb, kcb, qrb, qcb);
  scores_softmax_v2<<<dim3(4, 64, 2), 64, 0, stream>>>(qrb, qcb, krb, kcb, wrowB, wcolT);
  attn_kernel<<<640, 512, 0, stream>>>(wrowB, wcolT, vvT, part0, part1);
  gemm512_out<<<38, 512, 0, stream>>>(part0, part1, Wb + 327680, Bout, (float*)d_out);
}